// Round 5
// baseline (253.305 us; speedup 1.0000x reference)
//
#include <hip/hip_runtime.h>

#define M_DIM 2048
#define K_DIM 4096
#define N_DIM 4096

typedef unsigned short u16;
typedef unsigned int u32;
typedef __bf16 bf16x8 __attribute__((ext_vector_type(8)));
typedef float f32x16 __attribute__((ext_vector_type(16)));
typedef u16 u16x8 __attribute__((ext_vector_type(8)));

// fp32 -> bf16 round-to-nearest-even
__device__ __forceinline__ u16 f2bf(float f) {
    unsigned int u = __float_as_uint(f);
    u += 0x7fffu + ((u >> 16) & 1u);
    return (u16)(u >> 16);
}

// pack two fp32 -> (bf16(lo) | bf16(hi)<<16), RNE
__device__ __forceinline__ u32 pack2(float lo, float hi) {
    u32 a = __float_as_uint(lo); a += 0x7fffu + ((a >> 16) & 1u);
    u32 b = __float_as_uint(hi); b += 0x7fffu + ((b >> 16) & 1u);
    return (a >> 16) | (b & 0xffff0000u);
}

// async global->LDS, 16B per lane. LDS dest must be wave-uniform base + lane*16.
__device__ __forceinline__ void load16(const void* g, void* l) {
    __builtin_amdgcn_global_load_lds(
        (__attribute__((address_space(1))) const void*)g,
        (__attribute__((address_space(3))) void*)l,
        16, 0, 0);
}

// --------------- fused prep: x->bf16  AND  Bt = (mask? W:0)^T bf16 ----------
// UNCHANGED from R4 — HBM-bound at the 208 MB floor.
__global__ __launch_bounds__(256) void prep(const float* __restrict__ x,
                                            u16* __restrict__ xb,
                                            const float* __restrict__ W,
                                            const float* __restrict__ Msk,
                                            u16* __restrict__ Bt) {
    const int t = threadIdx.x;
    if (blockIdx.x >= 4096) {
        size_t i = ((size_t)(blockIdx.x - 4096) * 256 + t) * 8;
        float4 v0 = *(const float4*)(x + i);
        float4 v1 = *(const float4*)(x + i + 4);
        u16x8 o;
        o[0] = f2bf(v0.x); o[1] = f2bf(v0.y); o[2] = f2bf(v0.z); o[3] = f2bf(v0.w);
        o[4] = f2bf(v1.x); o[5] = f2bf(v1.y); o[6] = f2bf(v1.z); o[7] = f2bf(v1.w);
        *(u16x8*)(xb + i) = o;
        return;
    }
    __shared__ __align__(16) u32 T32[64 * 32];   // [n][kp swizzled]
    const int n0 = (blockIdx.x & 63) * 64;
    const int k0 = (blockIdx.x >> 6) * 64;

    const int kL     = (t >> 3) * 2;
    const int pchunk = ((t >> 3) >> 2) ^ (t & 7);
    const int word   = (t >> 3) & 3;
#pragma unroll
    for (int p = 0; p < 2; ++p) {
        const int n4 = (t & 7) * 4 + 32 * p;
        size_t g = (size_t)(k0 + kL) * N_DIM + n0 + n4;
        float4 w0 = *(const float4*)(W + g);
        float4 w1 = *(const float4*)(W + g + N_DIM);
        float4 m0 = *(const float4*)(Msk + g);
        float4 m1 = *(const float4*)(Msk + g + N_DIM);
        u32 v[4];
        v[0] = pack2(m0.x != 0.f ? w0.x : 0.f, m1.x != 0.f ? w1.x : 0.f);
        v[1] = pack2(m0.y != 0.f ? w0.y : 0.f, m1.y != 0.f ? w1.y : 0.f);
        v[2] = pack2(m0.z != 0.f ? w0.z : 0.f, m1.z != 0.f ? w1.z : 0.f);
        v[3] = pack2(m0.w != 0.f ? w0.w : 0.f, m1.w != 0.f ? w1.w : 0.f);
#pragma unroll
        for (int i = 0; i < 4; ++i)
            T32[(n4 + i) * 32 + pchunk * 4 + word] = v[i];
    }
    __syncthreads();

    const int rchunk = t & 7;
    const int rkey   = t >> 5;
    const int pc     = rchunk ^ rkey;
#pragma unroll
    for (int p = 0; p < 2; ++p) {
        const int n = (t >> 3) + 32 * p;
        uint4 v = *(const uint4*)&T32[n * 32 + pc * 4];
        *(uint4*)(Bt + (size_t)(n0 + n) * K_DIM + k0 + rchunk * 8) = v;
    }
}

// ------------- gemm: C = xb @ Bt^T + bias, 32x32x16 MFMA variant ------------
// 128x128 tile, BK=64, 4 waves in 2x2, each wave 2x2 of 32x32x16 MFMA.
// vs R3/R4 (16x16x32, 869 TF): same LDS traffic (reuse set by the 64x64 wave
// tile), but half the MFMA issue count and the 32x32 pipe's higher measured
// ceiling (m119: 2495 vs 2176 TF -> ~17% less MFMA-pipe time).
// Fragment layouts: A[m=lane&31][k=(lane>>5)*8+j], B mirror,
// C/D col=lane&31, row=(reg&3)+8*(reg>>2)+4*(lane>>5)   (m74/m101 verified).
// XOR swizzle: phys chunk = (2*ks + (lane>>5)) ^ (row&7), row&7 == lane&7;
// per instruction 64 lanes land exactly 8 per bank-group -> conflict-free.
__global__ __launch_bounds__(256) void gemm_bt(const u16* __restrict__ A,   // M x K bf16
                                               const u16* __restrict__ Bt,  // N x K bf16
                                               const float* __restrict__ bias,
                                               float* __restrict__ C) {
    __shared__ __align__(16) u16 As[128 * 64];
    __shared__ __align__(16) u16 Bs[128 * 64];

    const int t  = threadIdx.x;
    const int bn = blockIdx.x;
    const int bm = blockIdx.y;

    // staging (unchanged): lane stages swizzled k-chunk into fixed LDS slot
    const int srow   = t >> 3;
    const int schunk = (t & 7) ^ (srow & 7);
    const u16* gA = A  + (size_t)(bm * 128 + srow) * K_DIM + schunk * 8;
    const u16* gB = Bt + (size_t)(bn * 128 + srow) * K_DIM + schunk * 8;
    u16* lA = As + t * 8;
    u16* lB = Bs + t * 8;

    const int lane = t & 63;
    const int wave = t >> 6;
    const int wm = (wave >> 1) * 64;
    const int wn = (wave & 1) * 64;
    const int fm = lane & 31;          // fragment row (m or n)
    const int hi = lane >> 5;          // k-half selector
    const int lo7 = lane & 7;          // row-phase for XOR swizzle
    // physical u16 column of the 16B chunk holding k = ks*16 + hi*8
    int cols[4];
#pragma unroll
    for (int ks = 0; ks < 4; ++ks) cols[ks] = ((2 * ks + hi) ^ lo7) * 8;

    f32x16 acc[2][2] = {};

    for (int k0 = 0; k0 < K_DIM; k0 += 64) {
#pragma unroll
        for (int it = 0; it < 4; ++it) {
            load16(gA + k0 + it * 32 * K_DIM, lA + it * 2048);
            load16(gB + k0 + it * 32 * K_DIM, lB + it * 2048);
        }
        __syncthreads();   // drains vmcnt(0): staged data visible
#pragma unroll
        for (int ks = 0; ks < 4; ++ks) {
            const int col = cols[ks];
            bf16x8 af[2], bfr[2];
#pragma unroll
            for (int i = 0; i < 2; ++i)
                af[i] = *(const bf16x8*)(As + (wm + i * 32 + fm) * 64 + col);
#pragma unroll
            for (int j = 0; j < 2; ++j)
                bfr[j] = *(const bf16x8*)(Bs + (wn + j * 32 + fm) * 64 + col);
#pragma unroll
            for (int i = 0; i < 2; ++i)
#pragma unroll
                for (int j = 0; j < 2; ++j)
                    acc[i][j] = __builtin_amdgcn_mfma_f32_32x32x16_bf16(
                        af[i], bfr[j], acc[i][j], 0, 0, 0);
        }
        __syncthreads();   // all waves done reading before next stage
    }

    // epilogue: C/D col=lane&31 (n), row=(reg&3)+8*(reg>>2)+4*(lane>>5) (m)
#pragma unroll
    for (int j = 0; j < 2; ++j) {
        int n = bn * 128 + wn + j * 32 + fm;
        float bv = bias[n];
#pragma unroll
        for (int i = 0; i < 2; ++i) {
#pragma unroll
            for (int r = 0; r < 16; ++r) {
                int m = bm * 128 + wm + i * 32 + (r & 3) + 8 * (r >> 2) + 4 * hi;
                C[(size_t)m * N_DIM + n] = acc[i][j][r] + bv;
            }
        }
    }
}

extern "C" void kernel_launch(void* const* d_in, const int* in_sizes, int n_in,
                              void* d_out, int out_size, void* d_ws, size_t ws_size,
                              hipStream_t stream) {
    const float* x    = (const float*)d_in[0];  // 2048 x 4096
    const float* mask = (const float*)d_in[1];  // 4096 x 4096
    const float* W    = (const float*)d_in[2];  // 4096 x 4096
    const float* bias = (const float*)d_in[3];  // 4096
    float* out = (float*)d_out;                 // 2048 x 4096

    u16* Bt = (u16*)d_ws;                                   // N*K bf16 = 32 MB
    u16* xb = (u16*)d_ws + (size_t)N_DIM * K_DIM;           // M*K bf16 = 16 MB

    // prep signature is (x, xb, W, Msk, Bt) — keep argument order exact.
    prep<<<8192, 256, 0, stream>>>(x, xb, W, mask, Bt);
    gemm_bt<<<dim3(N_DIM / 128, M_DIM / 128), 256, 0, stream>>>(xb, Bt, bias, out);
}